// Round 2
// baseline (541.596 us; speedup 1.0000x reference)
//
#include <hip/hip_runtime.h>

typedef __bf16 bf16;
typedef __bf16 bf16x4 __attribute__((ext_vector_type(4)));
typedef __bf16 bf16x8 __attribute__((ext_vector_type(8)));
typedef float  f32x4  __attribute__((ext_vector_type(4)));

#define B_ 2048
#define T_ 128
#define C_ 256
#define H_ 64

// LDS layout (bytes):
//  phase1: xb0[128][72] @0 (18432), xb1[128][72] @18432  -> 36864 (dbuf x chunks)
//  phase2: Qs[128][72] @0, Ks[128][72] @18432, Vt[64][136] @36864 (17408) -> 54272
//  phase3: Ps[128][136] @0 (34816)
//  phase4: Of[128][68] f32 @0 (34816)
// 54272 * 3 = 162816 <= 163840 -> 3 blocks/CU
#define SMEM_BYTES 54272

// Weight transpose+convert: Wt[slot][h][c] bf16, slot 0=Wq,1=Wk,2=Wv. Coalesced reads.
__global__ void wt_kernel(const float* __restrict__ Wk, const float* __restrict__ Wq,
                          const float* __restrict__ Wv, bf16* __restrict__ Wt) {
    int o = blockIdx.x * 256 + threadIdx.x;     // 0..49151
    int slot = o >> 14;
    int r    = o & 16383;                       // (cc,h) c-major: coalesced read
    int cc   = r >> 6;
    int h    = r & 63;
    const float* src = (slot == 0) ? Wq : (slot == 1 ? Wk : Wv);
    Wt[slot * 16384 + h * 256 + cc] = (bf16)src[r];
}

__global__ void __launch_bounds__(256, 3)
attn_kernel(const float* __restrict__ xg, const bf16* __restrict__ Wt,
            float* __restrict__ outg) {
    __shared__ __align__(16) char smem_raw[SMEM_BYTES];
    bf16* xb0 = (bf16*)smem_raw;                 // [128][72]
    bf16* xb1 = (bf16*)(smem_raw + 18432);       // [128][72]
    bf16* Qs  = (bf16*)smem_raw;                 // [128][72]
    bf16* Ks  = (bf16*)(smem_raw + 18432);       // [128][72]
    bf16* Vt  = (bf16*)(smem_raw + 36864);       // [64][136]
    bf16* Ps  = (bf16*)smem_raw;                 // [128][136]
    float* Of = (float*)smem_raw;                // [128][68] fp32

    const int tid  = threadIdx.x;
    const int b    = blockIdx.x;
    const int w    = tid >> 6;
    const int lane = tid & 63;
    const int quad = lane >> 4;
    const int n16  = lane & 15;

    const f32x4 zero4 = {0.f, 0.f, 0.f, 0.f};

    // ---------------- projections: QKV = x @ [Wq|Wk|Wv] ----------------
    f32x4 acc[2][12];
    #pragma unroll
    for (int mt = 0; mt < 2; mt++)
        #pragma unroll
        for (int nt = 0; nt < 12; nt++) acc[mt][nt] = zero4;

    const float*  xb  = xg + (size_t)b * (T_ * C_);
    const ushort* WtU = (const ushort*)Wt;

    // prologue: load + stage chunk 0
    float4 xr[8];
    #pragma unroll
    for (int i = 0; i < 8; i++) {
        int f = tid + 256 * i;
        int t = f >> 4, c4 = (f & 15) * 4;
        xr[i] = *(const float4*)(xb + t * C_ + c4);
    }
    #pragma unroll
    for (int i = 0; i < 8; i++) {
        int f = tid + 256 * i;
        int t = f >> 4, c4 = (f & 15) * 4;
        bf16x4 bv = {(bf16)xr[i].x, (bf16)xr[i].y, (bf16)xr[i].z, (bf16)xr[i].w};
        *(bf16x4*)(xb0 + t * 72 + c4) = bv;
    }

    for (int c = 0; c < 4; c++) {
        // issue next chunk's global loads (regs only; fly across the MFMAs)
        if (c < 3) {
            #pragma unroll
            for (int i = 0; i < 8; i++) {
                int f = tid + 256 * i;
                int t = f >> 4, c4 = (f & 15) * 4;
                xr[i] = *(const float4*)(xb + t * C_ + (c + 1) * 64 + c4);
            }
        }
        __syncthreads();                         // chunk c staged; buf[(c+1)&1] free
        const bf16* xs = (c & 1) ? xb1 : xb0;
        bf16x8 a[2][2];
        #pragma unroll
        for (int mt = 0; mt < 2; mt++)
            #pragma unroll
            for (int ks = 0; ks < 2; ks++)
                a[mt][ks] = *(const bf16x8*)(xs + (16 * (2 * w + mt) + n16) * 72 + 32 * ks + 8 * quad);
        #pragma unroll
        for (int nt = 0; nt < 12; nt++) {
            // B-fragments straight from global W (L2-resident, shared by all blocks)
            const ushort* wp = WtU + (nt >> 2) * 16384 + (16 * (nt & 3) + n16) * 256 + c * 64 + 8 * quad;
            bf16x8 b0 = *(const bf16x8*)(wp);
            bf16x8 b1 = *(const bf16x8*)(wp + 32);
            #pragma unroll
            for (int mt = 0; mt < 2; mt++) {
                acc[mt][nt] = __builtin_amdgcn_mfma_f32_16x16x32_bf16(a[mt][0], b0, acc[mt][nt], 0, 0, 0);
                acc[mt][nt] = __builtin_amdgcn_mfma_f32_16x16x32_bf16(a[mt][1], b1, acc[mt][nt], 0, 0, 0);
            }
        }
        // convert + stage chunk c+1 (after MFMAs; barrier at next iter top publishes)
        if (c < 3) {
            bf16* dstb = (c & 1) ? xb0 : xb1;
            #pragma unroll
            for (int i = 0; i < 8; i++) {
                int f = tid + 256 * i;
                int t = f >> 4, c4 = (f & 15) * 4;
                bf16x4 bv = {(bf16)xr[i].x, (bf16)xr[i].y, (bf16)xr[i].z, (bf16)xr[i].w};
                *(bf16x4*)(dstb + t * 72 + c4) = bv;
            }
        }
    }
    __syncthreads();                             // all proj MFMA reads done; xbufs dead

    // write Q[t][h], K[s][h], Vt[h][t] as bf16 (C-layout: row=4*quad+r, col=n16)
    #pragma unroll
    for (int mt = 0; mt < 2; mt++) {
        int tbase = 16 * (2 * w + mt) + 4 * quad;
        #pragma unroll
        for (int nt = 0; nt < 8; nt++) {
            bf16* dst = (nt < 4) ? Qs : Ks;
            int h = 16 * (nt & 3) + n16;
            #pragma unroll
            for (int r = 0; r < 4; r++)
                dst[(tbase + r) * 72 + h] = (bf16)acc[mt][nt][r];
        }
        #pragma unroll
        for (int nt = 8; nt < 12; nt++) {        // V transposed: Vt[h][t]
            int h = 16 * (nt - 8) + n16;
            bf16x4 pv = {(bf16)acc[mt][nt][0], (bf16)acc[mt][nt][1],
                         (bf16)acc[mt][nt][2], (bf16)acc[mt][nt][3]};
            *(bf16x4*)(Vt + h * 136 + tbase) = pv;
        }
    }
    __syncthreads();

    // ---------------- S = Q K^T, causal softmax ----------------
    f32x4 sacc[2][8];
    int mts[2] = {w, 7 - w};
    #pragma unroll
    for (int half = 0; half < 2; half++) {
        int mt = mts[half];
        int sT = ((mt >> 1) + 1) * 2;
        bf16x8 qa[2];
        #pragma unroll
        for (int ks = 0; ks < 2; ks++)
            qa[ks] = *(const bf16x8*)(Qs + (16 * mt + n16) * 72 + 32 * ks + 8 * quad);
        #pragma unroll
        for (int nt = 0; nt < 8; nt++) {
            sacc[half][nt] = zero4;
            if (nt < sT) {
                bf16x8 kb0 = *(const bf16x8*)(Ks + (16 * nt + n16) * 72 + 8 * quad);
                bf16x8 kb1 = *(const bf16x8*)(Ks + (16 * nt + n16) * 72 + 32 + 8 * quad);
                sacc[half][nt] = __builtin_amdgcn_mfma_f32_16x16x32_bf16(qa[0], kb0, sacc[half][nt], 0, 0, 0);
                sacc[half][nt] = __builtin_amdgcn_mfma_f32_16x16x32_bf16(qa[1], kb1, sacc[half][nt], 0, 0, 0);
            }
        }
        #pragma unroll
        for (int r = 0; r < 4; r++) {
            int t = 16 * mt + 4 * quad + r;
            float mx = -3.0e38f;
            #pragma unroll
            for (int nt = 0; nt < 8; nt++) {
                if (nt < sT) {
                    float v = sacc[half][nt][r] * 0.0625f;       // scale = C^-0.5
                    v = (16 * nt + n16 <= t) ? v : -3.0e38f;     // causal mask
                    sacc[half][nt][r] = v;
                    mx = fmaxf(mx, v);
                }
            }
            mx = fmaxf(mx, __shfl_xor(mx, 1));
            mx = fmaxf(mx, __shfl_xor(mx, 2));
            mx = fmaxf(mx, __shfl_xor(mx, 4));
            mx = fmaxf(mx, __shfl_xor(mx, 8));
            float sum = 0.f;
            #pragma unroll
            for (int nt = 0; nt < 8; nt++) {
                if (nt < sT) {
                    float p = __builtin_amdgcn_exp2f((sacc[half][nt][r] - mx) * 1.4426950408889634f);
                    sacc[half][nt][r] = p;
                    sum += p;
                }
            }
            sum += __shfl_xor(sum, 1);
            sum += __shfl_xor(sum, 2);
            sum += __shfl_xor(sum, 4);
            sum += __shfl_xor(sum, 8);
            float rinv = 1.0f / sum;
            #pragma unroll
            for (int nt = 0; nt < 8; nt++)
                if (nt < sT) sacc[half][nt][r] *= rinv;
        }
    }
    __syncthreads();                             // Q/K reads done; Ps may alias

    #pragma unroll
    for (int half = 0; half < 2; half++) {
        int mt = mts[half];
        int sT = ((mt >> 1) + 1) * 2;
        #pragma unroll
        for (int nt = 0; nt < 8; nt++) {
            if (nt < sT) {
                #pragma unroll
                for (int r = 0; r < 4; r++)
                    Ps[(16 * mt + 4 * quad + r) * 136 + 16 * nt + n16] = (bf16)sacc[half][nt][r];
            }
        }
    }
    __syncthreads();

    // ---------------- O = P V ----------------
    f32x4 oacc[2][4];
    #pragma unroll
    for (int half = 0; half < 2; half++) {
        int mt  = mts[half];
        int kst = (mt >> 1) + 1;
        #pragma unroll
        for (int nt = 0; nt < 4; nt++) oacc[half][nt] = zero4;
        #pragma unroll
        for (int ks = 0; ks < 4; ks++) {
            if (ks < kst) {
                bf16x8 pa = *(const bf16x8*)(Ps + (16 * mt + n16) * 136 + 32 * ks + 8 * quad);
                #pragma unroll
                for (int nt = 0; nt < 4; nt++) {
                    bf16x8 vb = *(const bf16x8*)(Vt + (16 * nt + n16) * 136 + 32 * ks + 8 * quad);
                    oacc[half][nt] = __builtin_amdgcn_mfma_f32_16x16x32_bf16(pa, vb, oacc[half][nt], 0, 0, 0);
                }
            }
        }
    }
    __syncthreads();                             // PV reads done; Of aliases Ps

    // O -> LDS fp32 [128][68], then cooperative fully-coalesced float4 store
    #pragma unroll
    for (int half = 0; half < 2; half++) {
        int mt = mts[half];
        #pragma unroll
        for (int nt = 0; nt < 4; nt++)
            #pragma unroll
            for (int r = 0; r < 4; r++)
                Of[(16 * mt + 4 * quad + r) * 68 + 16 * nt + n16] = oacc[half][nt][r];
    }
    __syncthreads();
    #pragma unroll
    for (int i = 0; i < 8; i++) {
        int f = tid + 256 * i;
        int t = f >> 4, h4 = (f & 15) * 4;
        float4 v = *(const float4*)(Of + t * 68 + h4);
        *(float4*)(outg + ((size_t)b * T_ + t) * H_ + h4) = v;
    }
}

extern "C" void kernel_launch(void* const* d_in, const int* in_sizes, int n_in,
                              void* d_out, int out_size, void* d_ws, size_t ws_size,
                              hipStream_t stream) {
    const float* x  = (const float*)d_in[0];
    const float* Wk = (const float*)d_in[1];
    const float* Wq = (const float*)d_in[2];
    const float* Wv = (const float*)d_in[3];
    bf16* Wt = (bf16*)d_ws;                      // 3*64*256*2 = 98304 B scratch
    wt_kernel<<<192, 256, 0, stream>>>(Wk, Wq, Wv, Wt);
    attn_kernel<<<B_, 256, 0, stream>>>(x, Wt, (float*)d_out);
}

// Round 3
// 472.924 us; speedup vs baseline: 1.1452x; 1.1452x over previous
//
#include <hip/hip_runtime.h>

typedef __bf16 bf16;
typedef __bf16 bf16x4 __attribute__((ext_vector_type(4)));
typedef __bf16 bf16x8 __attribute__((ext_vector_type(8)));
typedef float  f32x4  __attribute__((ext_vector_type(4)));

#define B_ 2048
#define T_ 128
#define C_ 256
#define H_ 64

// LDS layout (bytes):
//  phase1: xs[128][264] bf16 @0 = 67584   (whole x tile, padded stride)
//  phase2: Qs[128][72] @0 (18432), Ks[128][72] @18432, Vt[64][136] @36864 (17408)
//  phase3: Ps[128][136] @0 (34816)   phase4: Of[128][68] f32 @0 (34816)
// high-water 67584 * 2 blocks = 135168 <= 163840 -> 2 blocks/CU
#define SMEM_BYTES 67584

__global__ void wt_kernel(const float* __restrict__ Wk, const float* __restrict__ Wq,
                          const float* __restrict__ Wv, bf16* __restrict__ Wt) {
    int o = blockIdx.x * 256 + threadIdx.x;     // 0..49151
    int slot = o >> 14;
    int r    = o & 16383;                       // coalesced source read
    int cc   = r >> 6;
    int h    = r & 63;
    const float* src = (slot == 0) ? Wq : (slot == 1 ? Wk : Wv);
    Wt[slot * 16384 + h * 256 + cc] = (bf16)src[r];
}

__global__ void __launch_bounds__(256, 2)
attn_kernel(const float* __restrict__ xg, const bf16* __restrict__ Wt,
            float* __restrict__ outg) {
    __shared__ __align__(16) char smem_raw[SMEM_BYTES];
    bf16* xs  = (bf16*)smem_raw;                 // [128][264]
    bf16* Qs  = (bf16*)smem_raw;                 // [128][72]
    bf16* Ks  = (bf16*)(smem_raw + 18432);       // [128][72]
    bf16* Vt  = (bf16*)(smem_raw + 36864);       // [64][136]
    bf16* Ps  = (bf16*)smem_raw;                 // [128][136]
    float* Of = (float*)smem_raw;                // [128][68]

    const int tid  = threadIdx.x;
    const int b    = blockIdx.x;
    const int w    = tid >> 6;
    const int lane = tid & 63;
    const int quad = lane >> 4;
    const int n16  = lane & 15;

    const f32x4 zero4 = {0.f, 0.f, 0.f, 0.f};
    const float*  xb  = xg + (size_t)b * (T_ * C_);
    const ushort* WtU = (const ushort*)Wt;

    // ---------------- phase 0: stage ALL of x (fp32->bf16), 2-deep pipelined ----------------
    // flat f = g*256 + tid over 8192 float4 groups: t = f>>6, c4 = (f&63)*4
    {
        float4 xa[8], xb4[8];
        #pragma unroll
        for (int i = 0; i < 8; i++) {
            int f = i * 256 + tid;
            xa[i] = *(const float4*)(xb + (f >> 6) * C_ + (f & 63) * 4);
        }
        #pragma unroll
        for (int g = 0; g < 4; g++) {
            float4* cur = (g & 1) ? xb4 : xa;
            float4* nxt = (g & 1) ? xa : xb4;
            if (g < 3) {
                #pragma unroll
                for (int i = 0; i < 8; i++) {
                    int f = (g + 1) * 2048 + i * 256 + tid;
                    nxt[i] = *(const float4*)(xb + (f >> 6) * C_ + (f & 63) * 4);
                }
            }
            #pragma unroll
            for (int i = 0; i < 8; i++) {
                int f = g * 2048 + i * 256 + tid;
                int t = f >> 6, c4 = (f & 63) * 4;
                bf16x4 bv = {(bf16)cur[i].x, (bf16)cur[i].y, (bf16)cur[i].z, (bf16)cur[i].w};
                *(bf16x4*)(xs + t * 264 + c4) = bv;
            }
        }
    }
    __syncthreads();

    // ---------------- phase 1: projections, K=256 in one MFMA-dense sweep ----------------
    f32x4 acc[2][12];
    #pragma unroll
    for (int mt = 0; mt < 2; mt++)
        #pragma unroll
        for (int nt = 0; nt < 12; nt++) acc[mt][nt] = zero4;

    #pragma unroll
    for (int ks = 0; ks < 8; ks++) {
        bf16x8 a[2];
        #pragma unroll
        for (int mt = 0; mt < 2; mt++)
            a[mt] = *(const bf16x8*)(xs + (16 * (2 * w + mt) + n16) * 264 + ks * 32 + 8 * quad);
        #pragma unroll
        for (int nt = 0; nt < 12; nt++) {
            // B-fragments from global Wt (96 KB, L2-resident, shared by all blocks)
            const ushort* wp = WtU + (nt >> 2) * 16384 + (16 * (nt & 3) + n16) * 256 + ks * 32 + 8 * quad;
            bf16x8 bfr = *(const bf16x8*)wp;
            acc[0][nt] = __builtin_amdgcn_mfma_f32_16x16x32_bf16(a[0], bfr, acc[0][nt], 0, 0, 0);
            acc[1][nt] = __builtin_amdgcn_mfma_f32_16x16x32_bf16(a[1], bfr, acc[1][nt], 0, 0, 0);
        }
    }
    __syncthreads();                             // proj reads done; xs dead

    // write Q[t][h], K[s][h], Vt[h][t] (C-layout: row=4*quad+r, col=n16)
    #pragma unroll
    for (int mt = 0; mt < 2; mt++) {
        int tbase = 16 * (2 * w + mt) + 4 * quad;
        #pragma unroll
        for (int nt = 0; nt < 8; nt++) {
            bf16* dst = (nt < 4) ? Qs : Ks;
            int h = 16 * (nt & 3) + n16;
            #pragma unroll
            for (int r = 0; r < 4; r++)
                dst[(tbase + r) * 72 + h] = (bf16)acc[mt][nt][r];
        }
        #pragma unroll
        for (int nt = 8; nt < 12; nt++) {        // V transposed: Vt[h][t]
            int h = 16 * (nt - 8) + n16;
            bf16x4 pv = {(bf16)acc[mt][nt][0], (bf16)acc[mt][nt][1],
                         (bf16)acc[mt][nt][2], (bf16)acc[mt][nt][3]};
            *(bf16x4*)(Vt + h * 136 + tbase) = pv;
        }
    }
    __syncthreads();

    // ---------------- S = Q K^T, causal softmax ----------------
    f32x4 sacc[2][8];
    int mts[2] = {w, 7 - w};
    #pragma unroll
    for (int half = 0; half < 2; half++) {
        int mt = mts[half];
        int sT = ((mt >> 1) + 1) * 2;
        bf16x8 qa[2];
        #pragma unroll
        for (int ks = 0; ks < 2; ks++)
            qa[ks] = *(const bf16x8*)(Qs + (16 * mt + n16) * 72 + 32 * ks + 8 * quad);
        #pragma unroll
        for (int nt = 0; nt < 8; nt++) {
            sacc[half][nt] = zero4;
            if (nt < sT) {
                bf16x8 kb0 = *(const bf16x8*)(Ks + (16 * nt + n16) * 72 + 8 * quad);
                bf16x8 kb1 = *(const bf16x8*)(Ks + (16 * nt + n16) * 72 + 32 + 8 * quad);
                sacc[half][nt] = __builtin_amdgcn_mfma_f32_16x16x32_bf16(qa[0], kb0, sacc[half][nt], 0, 0, 0);
                sacc[half][nt] = __builtin_amdgcn_mfma_f32_16x16x32_bf16(qa[1], kb1, sacc[half][nt], 0, 0, 0);
            }
        }
        #pragma unroll
        for (int r = 0; r < 4; r++) {
            int t = 16 * mt + 4 * quad + r;
            float mx = -3.0e38f;
            #pragma unroll
            for (int nt = 0; nt < 8; nt++) {
                if (nt < sT) {
                    float v = sacc[half][nt][r] * 0.0625f;       // scale = C^-0.5
                    v = (16 * nt + n16 <= t) ? v : -3.0e38f;     // causal
                    sacc[half][nt][r] = v;
                    mx = fmaxf(mx, v);
                }
            }
            mx = fmaxf(mx, __shfl_xor(mx, 1));
            mx = fmaxf(mx, __shfl_xor(mx, 2));
            mx = fmaxf(mx, __shfl_xor(mx, 4));
            mx = fmaxf(mx, __shfl_xor(mx, 8));
            float sum = 0.f;
            #pragma unroll
            for (int nt = 0; nt < 8; nt++) {
                if (nt < sT) {
                    float p = __builtin_amdgcn_exp2f((sacc[half][nt][r] - mx) * 1.4426950408889634f);
                    sacc[half][nt][r] = p;
                    sum += p;
                }
            }
            sum += __shfl_xor(sum, 1);
            sum += __shfl_xor(sum, 2);
            sum += __shfl_xor(sum, 4);
            sum += __shfl_xor(sum, 8);
            float rinv = 1.0f / sum;
            #pragma unroll
            for (int nt = 0; nt < 8; nt++)
                if (nt < sT) sacc[half][nt][r] *= rinv;
        }
    }
    __syncthreads();                             // Q/K reads done; Ps may alias

    #pragma unroll
    for (int half = 0; half < 2; half++) {
        int mt = mts[half];
        int sT = ((mt >> 1) + 1) * 2;
        #pragma unroll
        for (int nt = 0; nt < 8; nt++) {
            if (nt < sT) {
                #pragma unroll
                for (int r = 0; r < 4; r++)
                    Ps[(16 * mt + 4 * quad + r) * 136 + 16 * nt + n16] = (bf16)sacc[half][nt][r];
            }
        }
    }
    __syncthreads();

    // ---------------- O = P V ----------------
    f32x4 oacc[2][4];
    #pragma unroll
    for (int half = 0; half < 2; half++) {
        int mt  = mts[half];
        int kst = (mt >> 1) + 1;
        #pragma unroll
        for (int nt = 0; nt < 4; nt++) oacc[half][nt] = zero4;
        #pragma unroll
        for (int ks = 0; ks < 4; ks++) {
            if (ks < kst) {
                bf16x8 pa = *(const bf16x8*)(Ps + (16 * mt + n16) * 136 + 32 * ks + 8 * quad);
                #pragma unroll
                for (int nt = 0; nt < 4; nt++) {
                    bf16x8 vb = *(const bf16x8*)(Vt + (16 * nt + n16) * 136 + 32 * ks + 8 * quad);
                    oacc[half][nt] = __builtin_amdgcn_mfma_f32_16x16x32_bf16(pa, vb, oacc[half][nt], 0, 0, 0);
                }
            }
        }
    }
    __syncthreads();                             // PV reads done; Of aliases Ps

    #pragma unroll
    for (int half = 0; half < 2; half++) {
        int mt = mts[half];
        #pragma unroll
        for (int nt = 0; nt < 4; nt++)
            #pragma unroll
            for (int r = 0; r < 4; r++)
                Of[(16 * mt + 4 * quad + r) * 68 + 16 * nt + n16] = oacc[half][nt][r];
    }
    __syncthreads();
    #pragma unroll
    for (int i = 0; i < 8; i++) {
        int f = tid + 256 * i;
        int t = f >> 4, h4 = (f & 15) * 4;
        float4 v = *(const float4*)(Of + t * 68 + h4);
        *(float4*)(outg + ((size_t)b * T_ + t) * H_ + h4) = v;
    }
}

extern "C" void kernel_launch(void* const* d_in, const int* in_sizes, int n_in,
                              void* d_out, int out_size, void* d_ws, size_t ws_size,
                              hipStream_t stream) {
    const float* x  = (const float*)d_in[0];
    const float* Wk = (const float*)d_in[1];
    const float* Wq = (const float*)d_in[2];
    const float* Wv = (const float*)d_in[3];
    bf16* Wt = (bf16*)d_ws;                      // 98304 B scratch
    wt_kernel<<<192, 256, 0, stream>>>(Wk, Wq, Wv, Wt);
    attn_kernel<<<B_, 256, 0, stream>>>(x, Wt, (float*)d_out);
}